// Round 1
// baseline (77.706 us; speedup 1.0000x reference)
//
#include <hip/hip_runtime.h>
#include <math.h>

#define HH 512
#define WW 512
#define CPB 32   // columns per block
#define SEGS 8   // row segments per column
#define SEG 64   // rows per segment

// Block = (image, 32-column group). Thread = (column c, segment s).
// Computes per-pixel 1D nearest-False distance (both phases) via segmented
// scans, then d = sqrt((g^2 + (g&1))/2) (== reference's envelope result),
// accumulates sum(d*sel) and count(sel) per phase in doubles.
__global__ __launch_bounds__(256) void morph_main(
    const float* __restrict__ img, const float* __restrict__ msk,
    const float* __restrict__ tgt, double* __restrict__ partials)
{
  __shared__ int cF_f[SEGS][CPB], cF_b[SEGS][CPB];
  __shared__ int cB_f[SEGS][CPB], cB_b[SEGS][CPB];
  __shared__ int Xf[SEGS][CPB], Xb[SEGS][CPB];
  __shared__ int Yf[SEGS][CPB], Yb[SEGS][CPB];
  __shared__ double red[4][4];

  const int tid = threadIdx.x;
  const int blk = blockIdx.x;
  const int image = blk >> 4;            // 0 = img, 1 = target
  const int c0 = (blk & 15) * CPB;
  const float* __restrict__ src = image ? tgt : img;
  const int c = tid & 31;                // lane-major over columns: coalesced
  const int s = tid >> 5;                // segment 0..7
  const int col = c0 + c;
  const int rowbase = s * SEG;

  // ---- pass 1: load, binarize into register bitmasks, local carry scans ----
  unsigned long long bbits = 0ull, mbits = 0ull;
#pragma unroll
  for (int t = 0; t < SEG; ++t) {
    const int idx = (rowbase + t) * WW + col;
    const float v = src[idx];
    const float m = msk[idx];
    bbits |= (unsigned long long)(v > 0.22f) << t;
    mbits |= (unsigned long long)(m > 0.5f) << t;
  }
  int df = 4096, db = 4096;              // local-INF seed (> any real carry)
#pragma unroll
  for (int t = 0; t < SEG; ++t) {
    const int b = (int)((bbits >> t) & 1ull);
    df = b ? df + 1 : 0;                 // fg phase: dist to nearest False above
    db = b ? 0 : db + 1;                 // bg phase: dist to nearest True above
  }
  int uf = 4096, ub = 4096;
#pragma unroll
  for (int t = SEG - 1; t >= 0; --t) {
    const int b = (int)((bbits >> t) & 1ull);
    uf = b ? uf + 1 : 0;
    ub = b ? 0 : ub + 1;
  }
  cF_f[s][c] = df; cF_b[s][c] = db;      // fwd carry-out given INF carry-in
  cB_f[s][c] = uf; cB_b[s][c] = ub;      // bwd carry-out given INF carry-in
  __syncthreads();

  // ---- carry prefix across segments (scan op: x -> min(x+SEG, local)) ----
  if (tid < CPB) {
    int xf = 1024, xb = 1024;            // reference seeds carry = INF = H+W
    for (int ss = 0; ss < SEGS; ++ss) {
      Xf[ss][tid] = xf; Xb[ss][tid] = xb;
      xf = min(cF_f[ss][tid], xf + SEG);
      xb = min(cF_b[ss][tid], xb + SEG);
    }
    int yf = 1024, yb = 1024;
    for (int ss = SEGS - 1; ss >= 0; --ss) {
      Yf[ss][tid] = yf; Yb[ss][tid] = yb;
      yf = min(cB_f[ss][tid], yf + SEG);
      yb = min(cB_b[ss][tid], yb + SEG);
    }
  }
  __syncthreads();

  // ---- pass 2: exact forward distances with true carry-in (registers) ----
  unsigned int fwl[SEG];
  df = Xf[s][c]; db = Xb[s][c];
#pragma unroll
  for (int t = 0; t < SEG; ++t) {
    const int b = (int)((bbits >> t) & 1ull);
    df = b ? df + 1 : 0;
    db = b ? 0 : db + 1;
    fwl[t] = (unsigned)df | ((unsigned)db << 16);   // both <= 1600, fits u16
  }

  // ---- pass 3: backward distances, g, d, masked accumulation ----
  uf = Yf[s][c]; ub = Yb[s][c];
  double sum_f = 0.0, sum_b = 0.0;
  int cnt_f = 0, cnt_b = 0;
#pragma unroll
  for (int t = SEG - 1; t >= 0; --t) {
    const int b = (int)((bbits >> t) & 1ull);
    const int m = (int)((mbits >> t) & 1ull);
    uf = b ? uf + 1 : 0;
    ub = b ? 0 : ub + 1;
    const int gf = min(min((int)(fwl[t] & 0xffffu), uf), 1024);
    const int gb = min(min((int)(fwl[t] >> 16), ub), 1024);
    // d2 = (g^2 + (g odd)) / 2 exactly (integer < 2^24, exact in fp32);
    // all-True column => g == 1024 => reference d = 1024 exactly.
    const float dfv = (gf >= 1024) ? 1024.0f
                                   : sqrtf((float)(gf * gf + (gf & 1)) * 0.5f);
    const float dbv = (gb >= 1024) ? 1024.0f
                                   : sqrtf((float)(gb * gb + (gb & 1)) * 0.5f);
    const int self = b & m;        // fg phase & mask
    const int selb = (b ^ 1) & m;  // bg phase & mask
    sum_f += self ? (double)dfv : 0.0;
    sum_b += selb ? (double)dbv : 0.0;
    cnt_f += self;
    cnt_b += selb;
  }

  // ---- block reduction: wave shuffle, then LDS across 4 waves ----
#pragma unroll
  for (int off = 32; off > 0; off >>= 1) {
    sum_f += __shfl_down(sum_f, off);
    sum_b += __shfl_down(sum_b, off);
    cnt_f += __shfl_down(cnt_f, off);
    cnt_b += __shfl_down(cnt_b, off);
  }
  const int wv = tid >> 6;
  if ((tid & 63) == 0) {
    red[wv][0] = sum_f; red[wv][1] = sum_b;
    red[wv][2] = (double)cnt_f; red[wv][3] = (double)cnt_b;
  }
  __syncthreads();
  if (tid == 0) {
    double a = 0.0, bsum = 0.0, cf = 0.0, cb = 0.0;
    for (int w = 0; w < 4; ++w) {
      a += red[w][0]; bsum += red[w][1]; cf += red[w][2]; cb += red[w][3];
    }
    partials[blk * 4 + 0] = a;
    partials[blk * 4 + 1] = bsum;
    partials[blk * 4 + 2] = cf;
    partials[blk * 4 + 3] = cb;
  }
}

__global__ void morph_fin(const double* __restrict__ partials,
                          float* __restrict__ out)
{
  double sAf = 0, sAb = 0, cAf = 0, cAb = 0;
  double sBf = 0, sBb = 0, cBf = 0, cBb = 0;
  for (int blk = 0; blk < 16; ++blk) {
    sAf += partials[blk * 4 + 0]; sAb += partials[blk * 4 + 1];
    cAf += partials[blk * 4 + 2]; cAb += partials[blk * 4 + 3];
  }
  for (int blk = 16; blk < 32; ++blk) {
    sBf += partials[blk * 4 + 0]; sBb += partials[blk * 4 + 1];
    cBf += partials[blk * 4 + 2]; cBb += partials[blk * 4 + 3];
  }
  const double tl = 2.0 * 10.5 * sAf / fmax(cAf, 1.0);  // thicknessl (img)
  const double th = 2.0 * 10.5 * sBf / fmax(cBf, 1.0);  // thicknessh (target)
  const double sl = 2.0 * 10.5 * sAb / fmax(cAb, 1.0);  // separationl
  const double sh = 2.0 * 10.5 * sBb / fmax(cBb, 1.0);  // separationh
  double l1 = (tl - 48.7578) / 5.2874 - (th - 48.7578) / 5.2874;
  l1 *= l1;
  double l7 = (sl - 156.729) / 46.1809 - (sh - 156.729) / 46.1809;
  l7 *= l7;
  out[0] = (float)(0.5 * (l1 + l7));
}

extern "C" void kernel_launch(void* const* d_in, const int* in_sizes, int n_in,
                              void* d_out, int out_size, void* d_ws, size_t ws_size,
                              hipStream_t stream) {
  const float* img = (const float*)d_in[0];
  const float* msk = (const float*)d_in[1];
  const float* tgt = (const float*)d_in[2];
  double* partials = (double*)d_ws;  // 32 blocks * 4 doubles = 1 KiB
  morph_main<<<32, 256, 0, stream>>>(img, msk, tgt, partials);
  morph_fin<<<1, 1, 0, stream>>>(partials, (float*)d_out);
}